// Round 5
// baseline (227.660 us; speedup 1.0000x reference)
//
#include <hip/hip_runtime.h>
#include <math.h>

#define B_SZ 4096
#define N_PTS 2048
#define BLOCK 256

__device__ __forceinline__ float huber1(float a) {
    // a >= 0, delta = 1: 0.5*q*q + (a - q), q = min(a,1)
    float q = fminf(a, 1.0f);
    return 0.5f * q * q + (a - q);
}

// -------- Stage 1: long-lived streaming waves, no barriers, no atomics -----
// Grid = 512 blocks x 256 threads = 2048 waves. Each wave = one task:
//   blocks [0,256):   pc task  — wave handles a quad of 4 elements, one per
//                     16-lane group; each lane streams 32x2 float4 (rows x,y)
//   blocks [256,512): xd task  — same quad mapping; each lane streams 96 float4
// Reduction: width-16 shuffles at the very end (amortized over 64-96 KB).
__global__ __launch_bounds__(BLOCK) void loss_stage1(
    const float* __restrict__ point_cloud,      // (B,3,N)
    const float* __restrict__ x_delta,          // (B,3,N)
    const float* __restrict__ center_label,     // (B,3)
    float4* __restrict__ ws_pc,                 // (B,) {s_pp,s_pp2,s_t,s_t2}
    float*  __restrict__ ws_d)                  // (B,) s_d2
{
    const int tid  = threadIdx.x;
    const int wave = tid >> 6;
    const int lane = tid & 63;
    const int g    = lane >> 4;    // 16-lane group 0..3 -> element within quad
    const int il   = lane & 15;    // lane within group

    if (blockIdx.x < 256) {
        // ---- point-cloud projections ----
        const int quad = blockIdx.x * 4 + wave;   // 0..1023
        const int e    = quad * 4 + g;            // 0..4095

        const float cx = center_label[e * 3 + 0];
        const float cy = center_label[e * 3 + 1];
        const float vn = sqrtf(cx * cx + cy * cy);
        const float pdx = -cy / vn;
        const float pdy =  cx / vn;

        const float4* px = (const float4*)(point_cloud + (size_t)e * 3 * N_PTS); // row0: 512 f4
        const float4* py = px + (N_PTS / 4);                                      // row1

        float s_pp = 0.f, s_pp2 = 0.f, s_t = 0.f, s_t2 = 0.f;

        #pragma unroll 4
        for (int k = 0; k < N_PTS / 4 / 16; ++k) {   // 32 iters
            const float4 x4 = px[il + k * 16];
            const float4 y4 = py[il + k * 16];
            {
                const float pp = x4.x * pdx + y4.x * pdy;
                const float t  = x4.x * cx  + y4.x * cy;
                s_pp += pp; s_pp2 += pp * pp; s_t += t; s_t2 += t * t;
            }
            {
                const float pp = x4.y * pdx + y4.y * pdy;
                const float t  = x4.y * cx  + y4.y * cy;
                s_pp += pp; s_pp2 += pp * pp; s_t += t; s_t2 += t * t;
            }
            {
                const float pp = x4.z * pdx + y4.z * pdy;
                const float t  = x4.z * cx  + y4.z * cy;
                s_pp += pp; s_pp2 += pp * pp; s_t += t; s_t2 += t * t;
            }
            {
                const float pp = x4.w * pdx + y4.w * pdy;
                const float t  = x4.w * cx  + y4.w * cy;
                s_pp += pp; s_pp2 += pp * pp; s_t += t; s_t2 += t * t;
            }
        }

        // width-16 group reduction (only lane il==0's result is used)
        #pragma unroll
        for (int off = 8; off > 0; off >>= 1) {
            s_pp  += __shfl_down(s_pp,  off, 64);
            s_pp2 += __shfl_down(s_pp2, off, 64);
            s_t   += __shfl_down(s_t,   off, 64);
            s_t2  += __shfl_down(s_t2,  off, 64);
        }
        if (il == 0) ws_pc[e] = make_float4(s_pp, s_pp2, s_t, s_t2);
    } else {
        // ---- x_delta sum of squares ----
        const int quad = (blockIdx.x - 256) * 4 + wave;
        const int e    = quad * 4 + g;

        const float4* pd = (const float4*)(x_delta + (size_t)e * 3 * N_PTS); // 1536 f4

        float a0 = 0.f, a1 = 0.f, a2 = 0.f, a3 = 0.f;
        #pragma unroll 8
        for (int k = 0; k < 3 * N_PTS / 4 / 16; ++k) {   // 96 iters
            const float4 d = pd[il + k * 16];
            a0 += d.x * d.x;
            a1 += d.y * d.y;
            a2 += d.z * d.z;
            a3 += d.w * d.w;
        }
        float s = (a0 + a1) + (a2 + a3);

        #pragma unroll
        for (int off = 8; off > 0; off >>= 1)
            s += __shfl_down(s, off, 64);
        if (il == 0) ws_d[e] = s;
    }
}

// -------- Stage 2: per-element epilogue, one thread per element --------
__global__ __launch_bounds__(BLOCK) void loss_stage2(
    const float4* __restrict__ ws_pc,           // (B,)
    const float*  __restrict__ ws_d,            // (B,)
    const float* __restrict__ mask_xyz_mean,    // (B,3)
    const float* __restrict__ center_label,     // (B,3)
    const float* __restrict__ size_residual,    // (B,3)
    const float* __restrict__ heading_residual, // (B,)
    const float* __restrict__ mean_sizes,       // (8,3)
    const int*   __restrict__ size_class,       // (B,)
    const int*   __restrict__ heading_class,    // (B,)
    float* __restrict__ ws_p)                   // (gridDim.x) partials
{
    const int tid = threadIdx.x;
    const int b   = blockIdx.x * BLOCK + tid;   // grid covers exactly B_SZ

    const float4 pcs = ws_pc[b];
    const float s_pp = pcs.x, s_pp2 = pcs.y, s_t = pcs.z, s_t2 = pcs.w;
    const float s_d2 = ws_d[b];

    const float cx = center_label[b * 3 + 0];
    const float cy = center_label[b * 3 + 1];
    const float cz = center_label[b * 3 + 2];
    const float vnorm2 = cx * cx + cy * cy;
    const float vnorm  = sqrtf(vnorm2);
    const float pdx = -cy / vnorm;
    const float pdy =  cx / vnorm;

    const float mx = mask_xyz_mean[b * 3 + 0];
    const float my = mask_xyz_mean[b * 3 + 1];
    const float mz = mask_xyz_mean[b * 3 + 2];
    const float dxc = mx - cx, dyc = my - cy, dzc = mz - cz;
    const float center_dist = sqrtf(dxc * dxc + dyc * dyc + dzc * dzc);

    const int sc = size_class[b];
    const float l  = mean_sizes[sc * 3 + 0] + size_residual[b * 3 + 0];
    const float w_ = mean_sizes[sc * 3 + 1] + size_residual[b * 3 + 1];
    // h (size z) does not affect the 2D corners used below

    const float theta = heading_residual[b] +
                        (float)heading_class[b] * (float)(M_PI / 12.0);
    const float c = cosf(theta);
    const float s = sinf(theta);
    const float hl = 0.5f * l, hw = 0.5f * w_;

    // bottom corners k=4..7: sx={1,1,-1,-1}, sy={1,-1,-1,1}
    float X[4], Y[4];
    X[0] =  c * hl - s * hw + cx;  Y[0] =  s * hl + c * hw + cy;
    X[1] =  c * hl + s * hw + cx;  Y[1] =  s * hl - c * hw + cy;
    X[2] = -c * hl + s * hw + cx;  Y[2] = -s * hl - c * hw + cy;
    X[3] = -c * hl - s * hw + cx;  Y[3] = -s * hl + c * hw + cy;

    float ppmax = -INFINITY, ppmin = INFINITY;
    float pmax  = -INFINITY, pmin  = INFINITY;
    #pragma unroll
    for (int k = 0; k < 4; ++k) {
        const float pp = X[k] * pdx + Y[k] * pdy;
        const float pj = (X[k] * cx + Y[k] * cy) / vnorm;
        ppmax = fmaxf(ppmax, pp); ppmin = fminf(ppmin, pp);
        pmax  = fmaxf(pmax,  pj); pmin  = fminf(pmin,  pj);
    }
    const float std_y_label  = (ppmax - ppmin) * 0.25f;
    const float mean_y_label = (ppmax + ppmin) * 0.5f;
    const float std_label    = (pmax - pmin) * 0.25f;
    const float mean_label   = (pmax + pmin) * 0.5f;

    const float invN   = 1.0f / (float)N_PTS;
    const float invNm1 = 1.0f / (float)(N_PTS - 1);

    const float mean_y_pc = s_pp * invN;
    const float var_y = (s_pp2 - s_pp * s_pp * invN) * invNm1;
    const float std_y_pc = sqrtf(fmaxf(var_y, 0.0f));

    const float mean_pc = (s_t * invN) / vnorm;
    const float var_x = ((s_t2 - s_t * s_t * invN) * invNm1) / vnorm2;
    const float std_pc = sqrtf(fmaxf(var_x, 0.0f));

    const float delta_norm = sqrtf(s_d2);

    float total =
          0.5f  * huber1(center_dist)
        +         huber1(fabsf(std_label  - std_pc))
        +         huber1(fabsf(mean_label - mean_pc))
        + 0.01f * huber1(delta_norm)
        +         huber1(fabsf(mean_y_label - mean_y_pc))
        +         huber1(fabsf(std_y_label  - std_y_pc));

    // block reduction -> one partial per block
    #pragma unroll
    for (int off = 32; off > 0; off >>= 1)
        total += __shfl_down(total, off, 64);

    __shared__ float red[BLOCK / 64];
    const int wave = tid >> 6;
    const int lane = tid & 63;
    if (lane == 0) red[wave] = total;
    __syncthreads();
    if (tid == 0) {
        #pragma unroll
        for (int w = 1; w < BLOCK / 64; ++w) total += red[w];
        ws_p[blockIdx.x] = total;
    }
}

// -------- Stage 3: 16 partials -> scalar output --------
__global__ void loss_stage3(const float* __restrict__ ws_p, float* __restrict__ out)
{
    const int lane = threadIdx.x;
    float s = (lane < B_SZ / BLOCK) ? ws_p[lane] : 0.0f;
    #pragma unroll
    for (int off = 32; off > 0; off >>= 1)
        s += __shfl_down(s, off, 64);
    if (lane == 0) out[0] = s * (0.4f / (float)B_SZ);
}

extern "C" void kernel_launch(void* const* d_in, const int* in_sizes, int n_in,
                              void* d_out, int out_size, void* d_ws, size_t ws_size,
                              hipStream_t stream) {
    const float* mask_xyz_mean    = (const float*)d_in[0];
    const float* point_cloud      = (const float*)d_in[1];
    const float* x_delta          = (const float*)d_in[2];
    const float* center_label     = (const float*)d_in[3];
    const float* size_residual    = (const float*)d_in[4];
    const float* heading_residual = (const float*)d_in[5];
    const float* mean_sizes       = (const float*)d_in[6];
    const int*   size_class       = (const int*)d_in[7];
    const int*   heading_class    = (const int*)d_in[8];
    float* out = (float*)d_out;

    // workspace layout: 4096 float4 | 4096 float | 16 float  (= 82 KB)
    float4* ws_pc = (float4*)d_ws;
    float*  ws_d  = (float*)d_ws + B_SZ * 4;
    float*  ws_p  = ws_d + B_SZ;

    loss_stage1<<<512, BLOCK, 0, stream>>>(
        point_cloud, x_delta, center_label, ws_pc, ws_d);
    loss_stage2<<<B_SZ / BLOCK, BLOCK, 0, stream>>>(
        ws_pc, ws_d, mask_xyz_mean, center_label, size_residual,
        heading_residual, mean_sizes, size_class, heading_class, ws_p);
    loss_stage3<<<1, 64, 0, stream>>>(ws_p, out);
}

// Round 6
// 222.788 us; speedup vs baseline: 1.0219x; 1.0219x over previous
//
#include <hip/hip_runtime.h>
#include <math.h>

#define B_SZ 4096
#define N_PTS 2048
#define BLOCK 256

__device__ __forceinline__ float huber1(float a) {
    // a >= 0, delta = 1: 0.5*q*q + (a - q), q = min(a,1)
    float q = fminf(a, 1.0f);
    return 0.5f * q * q + (a - q);
}

// -------- Stage 1: wave-autonomous streaming. No LDS, no barriers. --------
// blocks [0,1024):    pc — wave = one element; 64 lanes sweep rows 0/1
//                     (full-wave 1 KB coalescing), 16 loads, unroll 4.
// blocks [1024,5120): xd — wave = one quarter-segment (384 float4);
//                     6 loads all in flight; partial -> ws_dq[w].
__global__ __launch_bounds__(BLOCK) void loss_stage1(
    const float* __restrict__ point_cloud,      // (B,3,N)
    const float* __restrict__ x_delta,          // (B,3,N)
    const float* __restrict__ center_label,     // (B,3)
    float4* __restrict__ ws_pc,                 // (B,) {s_pp,s_pp2,s_t,s_t2}
    float*  __restrict__ ws_dq)                 // (4B,) quarter-segment d2 partials
{
    const int tid  = threadIdx.x;
    const int wave = tid >> 6;
    const int lane = tid & 63;

    if (blockIdx.x < 1024) {
        // ---- point-cloud projections: one wave per element ----
        const int e = blockIdx.x * 4 + wave;    // 0..4095

        const float cx = center_label[e * 3 + 0];
        const float cy = center_label[e * 3 + 1];
        const float vn = sqrtf(cx * cx + cy * cy);
        const float pdx = -cy / vn;
        const float pdy =  cx / vn;

        const float4* px = (const float4*)(point_cloud + (size_t)e * 3 * N_PTS); // row0: 512 f4
        const float4* py = px + (N_PTS / 4);                                      // row1

        float s_pp = 0.f, s_pp2 = 0.f, s_t = 0.f, s_t2 = 0.f;

        #pragma unroll 4
        for (int k = 0; k < N_PTS / 4 / 64; ++k) {   // 8 iters, 2 loads each
            const float4 x4 = px[lane + k * 64];
            const float4 y4 = py[lane + k * 64];
            {
                const float pp = x4.x * pdx + y4.x * pdy;
                const float t  = x4.x * cx  + y4.x * cy;
                s_pp += pp; s_pp2 += pp * pp; s_t += t; s_t2 += t * t;
            }
            {
                const float pp = x4.y * pdx + y4.y * pdy;
                const float t  = x4.y * cx  + y4.y * cy;
                s_pp += pp; s_pp2 += pp * pp; s_t += t; s_t2 += t * t;
            }
            {
                const float pp = x4.z * pdx + y4.z * pdy;
                const float t  = x4.z * cx  + y4.z * cy;
                s_pp += pp; s_pp2 += pp * pp; s_t += t; s_t2 += t * t;
            }
            {
                const float pp = x4.w * pdx + y4.w * pdy;
                const float t  = x4.w * cx  + y4.w * cy;
                s_pp += pp; s_pp2 += pp * pp; s_t += t; s_t2 += t * t;
            }
        }

        // width-64 shuffle reduction, then single store from lane 0
        #pragma unroll
        for (int off = 32; off > 0; off >>= 1) {
            s_pp  += __shfl_down(s_pp,  off, 64);
            s_pp2 += __shfl_down(s_pp2, off, 64);
            s_t   += __shfl_down(s_t,   off, 64);
            s_t2  += __shfl_down(s_t2,  off, 64);
        }
        if (lane == 0) ws_pc[e] = make_float4(s_pp, s_pp2, s_t, s_t2);
    } else {
        // ---- x_delta sum of squares: one wave per quarter-segment ----
        const int w = (blockIdx.x - 1024) * 4 + wave;   // 0..16383
        const int s_idx = w >> 2;                        // element
        const int q     = w & 3;                         // quarter

        const float4* pd = (const float4*)x_delta +
                           (size_t)s_idx * 1536 + q * 384;

        // 6 independent loads, all in flight
        float4 d0 = pd[lane];
        float4 d1 = pd[lane + 64];
        float4 d2 = pd[lane + 128];
        float4 d3 = pd[lane + 192];
        float4 d4 = pd[lane + 256];
        float4 d5 = pd[lane + 320];

        float a0 = d0.x * d0.x + d0.y * d0.y + d0.z * d0.z + d0.w * d0.w;
        float a1 = d1.x * d1.x + d1.y * d1.y + d1.z * d1.z + d1.w * d1.w;
        float a2 = d2.x * d2.x + d2.y * d2.y + d2.z * d2.z + d2.w * d2.w;
        float a3 = d3.x * d3.x + d3.y * d3.y + d3.z * d3.z + d3.w * d3.w;
        float a4 = d4.x * d4.x + d4.y * d4.y + d4.z * d4.z + d4.w * d4.w;
        float a5 = d5.x * d5.x + d5.y * d5.y + d5.z * d5.z + d5.w * d5.w;
        float s = ((a0 + a1) + (a2 + a3)) + (a4 + a5);

        #pragma unroll
        for (int off = 32; off > 0; off >>= 1)
            s += __shfl_down(s, off, 64);
        if (lane == 0) ws_dq[w] = s;
    }
}

// -------- Stage 2: per-element epilogue, one thread per element --------
__global__ __launch_bounds__(BLOCK) void loss_stage2(
    const float4* __restrict__ ws_pc,           // (B,)
    const float4* __restrict__ ws_dq4,          // (B,) four quarter-partials
    const float* __restrict__ mask_xyz_mean,    // (B,3)
    const float* __restrict__ center_label,     // (B,3)
    const float* __restrict__ size_residual,    // (B,3)
    const float* __restrict__ heading_residual, // (B,)
    const float* __restrict__ mean_sizes,       // (8,3)
    const int*   __restrict__ size_class,       // (B,)
    const int*   __restrict__ heading_class,    // (B,)
    float* __restrict__ ws_p)                   // (gridDim.x) partials
{
    const int tid = threadIdx.x;
    const int b   = blockIdx.x * BLOCK + tid;   // grid covers exactly B_SZ

    const float4 pcs = ws_pc[b];
    const float s_pp = pcs.x, s_pp2 = pcs.y, s_t = pcs.z, s_t2 = pcs.w;
    const float4 dq = ws_dq4[b];
    const float s_d2 = (dq.x + dq.y) + (dq.z + dq.w);

    const float cx = center_label[b * 3 + 0];
    const float cy = center_label[b * 3 + 1];
    const float cz = center_label[b * 3 + 2];
    const float vnorm2 = cx * cx + cy * cy;
    const float vnorm  = sqrtf(vnorm2);
    const float pdx = -cy / vnorm;
    const float pdy =  cx / vnorm;

    const float mx = mask_xyz_mean[b * 3 + 0];
    const float my = mask_xyz_mean[b * 3 + 1];
    const float mz = mask_xyz_mean[b * 3 + 2];
    const float dxc = mx - cx, dyc = my - cy, dzc = mz - cz;
    const float center_dist = sqrtf(dxc * dxc + dyc * dyc + dzc * dzc);

    const int sc = size_class[b];
    const float l  = mean_sizes[sc * 3 + 0] + size_residual[b * 3 + 0];
    const float w_ = mean_sizes[sc * 3 + 1] + size_residual[b * 3 + 1];
    // h (size z) does not affect the 2D corners used below

    const float theta = heading_residual[b] +
                        (float)heading_class[b] * (float)(M_PI / 12.0);
    const float c = cosf(theta);
    const float s = sinf(theta);
    const float hl = 0.5f * l, hw = 0.5f * w_;

    // bottom corners k=4..7: sx={1,1,-1,-1}, sy={1,-1,-1,1}
    float X[4], Y[4];
    X[0] =  c * hl - s * hw + cx;  Y[0] =  s * hl + c * hw + cy;
    X[1] =  c * hl + s * hw + cx;  Y[1] =  s * hl - c * hw + cy;
    X[2] = -c * hl + s * hw + cx;  Y[2] = -s * hl - c * hw + cy;
    X[3] = -c * hl - s * hw + cx;  Y[3] = -s * hl + c * hw + cy;

    float ppmax = -INFINITY, ppmin = INFINITY;
    float pmax  = -INFINITY, pmin  = INFINITY;
    #pragma unroll
    for (int k = 0; k < 4; ++k) {
        const float pp = X[k] * pdx + Y[k] * pdy;
        const float pj = (X[k] * cx + Y[k] * cy) / vnorm;
        ppmax = fmaxf(ppmax, pp); ppmin = fminf(ppmin, pp);
        pmax  = fmaxf(pmax,  pj); pmin  = fminf(pmin,  pj);
    }
    const float std_y_label  = (ppmax - ppmin) * 0.25f;
    const float mean_y_label = (ppmax + ppmin) * 0.5f;
    const float std_label    = (pmax - pmin) * 0.25f;
    const float mean_label   = (pmax + pmin) * 0.5f;

    const float invN   = 1.0f / (float)N_PTS;
    const float invNm1 = 1.0f / (float)(N_PTS - 1);

    const float mean_y_pc = s_pp * invN;
    const float var_y = (s_pp2 - s_pp * s_pp * invN) * invNm1;
    const float std_y_pc = sqrtf(fmaxf(var_y, 0.0f));

    const float mean_pc = (s_t * invN) / vnorm;
    const float var_x = ((s_t2 - s_t * s_t * invN) * invNm1) / vnorm2;
    const float std_pc = sqrtf(fmaxf(var_x, 0.0f));

    const float delta_norm = sqrtf(s_d2);

    float total =
          0.5f  * huber1(center_dist)
        +         huber1(fabsf(std_label  - std_pc))
        +         huber1(fabsf(mean_label - mean_pc))
        + 0.01f * huber1(delta_norm)
        +         huber1(fabsf(mean_y_label - mean_y_pc))
        +         huber1(fabsf(std_y_label  - std_y_pc));

    // block reduction -> one partial per block
    #pragma unroll
    for (int off = 32; off > 0; off >>= 1)
        total += __shfl_down(total, off, 64);

    __shared__ float red[BLOCK / 64];
    const int wave = tid >> 6;
    const int lane = tid & 63;
    if (lane == 0) red[wave] = total;
    __syncthreads();
    if (tid == 0) {
        #pragma unroll
        for (int w = 1; w < BLOCK / 64; ++w) total += red[w];
        ws_p[blockIdx.x] = total;
    }
}

// -------- Stage 3: 16 partials -> scalar output --------
__global__ void loss_stage3(const float* __restrict__ ws_p, float* __restrict__ out)
{
    const int lane = threadIdx.x;
    float s = (lane < B_SZ / BLOCK) ? ws_p[lane] : 0.0f;
    #pragma unroll
    for (int off = 32; off > 0; off >>= 1)
        s += __shfl_down(s, off, 64);
    if (lane == 0) out[0] = s * (0.4f / (float)B_SZ);
}

extern "C" void kernel_launch(void* const* d_in, const int* in_sizes, int n_in,
                              void* d_out, int out_size, void* d_ws, size_t ws_size,
                              hipStream_t stream) {
    const float* mask_xyz_mean    = (const float*)d_in[0];
    const float* point_cloud      = (const float*)d_in[1];
    const float* x_delta          = (const float*)d_in[2];
    const float* center_label     = (const float*)d_in[3];
    const float* size_residual    = (const float*)d_in[4];
    const float* heading_residual = (const float*)d_in[5];
    const float* mean_sizes       = (const float*)d_in[6];
    const int*   size_class       = (const int*)d_in[7];
    const int*   heading_class    = (const int*)d_in[8];
    float* out = (float*)d_out;

    // workspace: 4096 float4 (64 KB) | 16384 float (64 KB) | 16 float
    float4* ws_pc = (float4*)d_ws;
    float*  ws_dq = (float*)d_ws + B_SZ * 4;
    float*  ws_p  = ws_dq + B_SZ * 4;

    loss_stage1<<<5120, BLOCK, 0, stream>>>(
        point_cloud, x_delta, center_label, ws_pc, ws_dq);
    loss_stage2<<<B_SZ / BLOCK, BLOCK, 0, stream>>>(
        ws_pc, (const float4*)ws_dq, mask_xyz_mean, center_label, size_residual,
        heading_residual, mean_sizes, size_class, heading_class, ws_p);
    loss_stage3<<<1, 64, 0, stream>>>(ws_p, out);
}